// Round 1
// baseline (295.015 us; speedup 1.0000x reference)
//
#include <hip/hip_runtime.h>
#include <math.h>

// Stable softplus: log(1+exp(x)) = max(x,0) + log1p(exp(-|x|))
__device__ __forceinline__ float softplus_f(float x) {
    return fmaxf(x, 0.0f) + log1pf(expf(-fabsf(x)));
}

// One thread per row i in [0,B). Each row contributes:
//   bce_bin(i) + mean_j bce_type(i,j) + ce(i) + xor(bin,type) + xor(bin,src)
// Loss = (1/B) * sum of contributions.
__global__ __launch_bounds__(256) void multitask_loss_kernel(
    const float*  __restrict__ pb,   // [B]
    const float4* __restrict__ pt,   // [B,4]  as float4 per row
    const float4* __restrict__ ps,   // [B,16] as 4x float4 per row
    const float*  __restrict__ tb,   // [B]
    const float4* __restrict__ tt,   // [B,4]
    const int*    __restrict__ ts,   // [B]
    double*       __restrict__ acc,  // [1] global accumulator (pre-zeroed)
    int B)
{
    int i = blockIdx.x * blockDim.x + threadIdx.x;
    float contrib = 0.0f;
    if (i < B) {
        // ---- binary BCE: y*softplus(-x) + (1-y)*softplus(x) == softplus(x) - y*x
        float x = pb[i];
        float y = tb[i];
        contrib = softplus_f(x) - y * x;
        bool bin_c = (x >= 0.0f);   // round(sigmoid(x)) with >= tie at 0.5

        // ---- type BCE (mean over 4) + any(sigmoid >= 0.5)
        float4 xt = pt[i];
        float4 yt = tt[i];
        float tsum = (softplus_f(xt.x) - yt.x * xt.x)
                   + (softplus_f(xt.y) - yt.y * xt.y)
                   + (softplus_f(xt.z) - yt.z * xt.z)
                   + (softplus_f(xt.w) - yt.w * xt.w);
        contrib += 0.25f * tsum;
        bool type_c = (xt.x >= 0.0f) || (xt.y >= 0.0f) ||
                      (xt.z >= 0.0f) || (xt.w >= 0.0f);

        // ---- source CE over 16 classes: lse(v) - v[label]
        size_t base = (size_t)i * 4;
        float4 r0 = ps[base + 0];
        float4 r1 = ps[base + 1];
        float4 r2 = ps[base + 2];
        float4 r3 = ps[base + 3];
        float v[16] = { r0.x, r0.y, r0.z, r0.w,
                        r1.x, r1.y, r1.z, r1.w,
                        r2.x, r2.y, r2.z, r2.w,
                        r3.x, r3.y, r3.z, r3.w };
        float m = v[0];
        #pragma unroll
        for (int j = 1; j < 16; ++j) m = fmaxf(m, v[j]);
        float s = 0.0f;
        #pragma unroll
        for (int j = 0; j < 16; ++j) s += expf(v[j] - m);
        int lab = ts[i];
        float vlab = v[0];
        #pragma unroll
        for (int j = 1; j < 16; ++j) vlab = (lab == j) ? v[j] : vlab;  // unrolled select, stays in regs
        contrib += m + logf(s) - vlab;

        // argmax(v) > 0  <=>  exists j>0 with v[j] > v[0]  (first-max tie-break)
        float max_rest = v[1];
        #pragma unroll
        for (int j = 2; j < 16; ++j) max_rest = fmaxf(max_rest, v[j]);
        bool src_c = (max_rest > v[0]);

        // ---- consistency XOR penalties
        contrib += (bin_c != type_c) ? 1.0f : 0.0f;
        contrib += (bin_c != src_c)  ? 1.0f : 0.0f;
    }

    // ---- wave-64 shuffle reduction
    #pragma unroll
    for (int off = 32; off > 0; off >>= 1)
        contrib += __shfl_down(contrib, off, 64);

    __shared__ float wsum[4];
    int lane = threadIdx.x & 63;
    int wave = threadIdx.x >> 6;
    if (lane == 0) wsum[wave] = contrib;
    __syncthreads();
    if (threadIdx.x == 0) {
        float bsum = wsum[0] + wsum[1] + wsum[2] + wsum[3];
        atomicAdd(acc, (double)bsum);   // double: avoids float drift over 8192 adds
    }
}

__global__ void finalize_kernel(const double* __restrict__ acc,
                                float* __restrict__ out, double invB) {
    out[0] = (float)(acc[0] * invB);
}

extern "C" void kernel_launch(void* const* d_in, const int* in_sizes, int n_in,
                              void* d_out, int out_size, void* d_ws, size_t ws_size,
                              hipStream_t stream) {
    const float*  pb = (const float*)d_in[0];
    const float4* pt = (const float4*)d_in[1];
    const float4* ps = (const float4*)d_in[2];
    const float*  tb = (const float*)d_in[3];
    const float4* tt = (const float4*)d_in[4];
    const int*    ts = (const int*)d_in[5];
    int B = in_sizes[0];

    double* acc = (double*)d_ws;
    hipMemsetAsync(d_ws, 0, sizeof(double), stream);  // ws is poisoned 0xAA every call

    int blocks = (B + 255) / 256;
    multitask_loss_kernel<<<blocks, 256, 0, stream>>>(pb, pt, ps, tb, tt, ts, acc, B);
    finalize_kernel<<<1, 1, 0, stream>>>(acc, (float*)d_out, 1.0 / (double)B);
}

// Round 2
// 271.558 us; speedup vs baseline: 1.0864x; 1.0864x over previous
//
#include <hip/hip_runtime.h>
#include <math.h>

// Fast softplus using HW v_exp_f32 / v_log_f32 (accuracy ~2 ulp — threshold is 0.117):
// softplus(x) = max(x,0) + log(1 + exp(-|x|))
__device__ __forceinline__ float fast_softplus(float x) {
    return fmaxf(x, 0.0f) + __logf(1.0f + __expf(-fabsf(x)));
}

// Contribution of one row: bce_bin + mean4(bce_type) + ce16 + xor(bin,type) + xor(bin,src)
__device__ __forceinline__ float row_contrib(float xb, float yb,
                                             float4 xt, float4 yt,
                                             const float v[16], int lab)
{
    float c = fast_softplus(xb) - yb * xb;      // BCE: softplus(x) - y*x
    bool bin_c = (xb >= 0.0f);

    float tsum = (fast_softplus(xt.x) - yt.x * xt.x)
               + (fast_softplus(xt.y) - yt.y * xt.y)
               + (fast_softplus(xt.z) - yt.z * xt.z)
               + (fast_softplus(xt.w) - yt.w * xt.w);
    c += 0.25f * tsum;
    bool type_c = (xt.x >= 0.0f) || (xt.y >= 0.0f) ||
                  (xt.z >= 0.0f) || (xt.w >= 0.0f);

    // 16-class CE: lse(v) - v[lab]
    float m = v[0];
    #pragma unroll
    for (int j = 1; j < 16; ++j) m = fmaxf(m, v[j]);
    float s = 0.0f;
    #pragma unroll
    for (int j = 0; j < 16; ++j) s += __expf(v[j] - m);
    float vlab = v[0];
    #pragma unroll
    for (int j = 1; j < 16; ++j) vlab = (lab == j) ? v[j] : vlab;
    c += m + __logf(s) - vlab;

    // argmax(v) > 0  <=>  max(v[1:]) > v[0] (first-max tie-break)
    float mr = v[1];
    #pragma unroll
    for (int j = 2; j < 16; ++j) mr = fmaxf(mr, v[j]);
    bool src_c = (mr > v[0]);

    c += (bin_c != type_c) ? 1.0f : 0.0f;
    c += (bin_c != src_c)  ? 1.0f : 0.0f;
    return c;
}

// 4 consecutive rows per thread: pb/tb/ts load as one dwordx4 each,
// pt/tt as 4 dwordx4, ps as 16 dwordx4. High MLP, few load instructions.
__global__ __launch_bounds__(256) void multitask_loss_kernel(
    const float4* __restrict__ pb4,  // [B/4]
    const float4* __restrict__ pt4,  // [B]   (one float4 per row)
    const float4* __restrict__ ps4,  // [B*4] (four float4 per row)
    const float4* __restrict__ tb4,  // [B/4]
    const float4* __restrict__ tt4,  // [B]
    const int4*   __restrict__ ts4,  // [B/4]
    float*        __restrict__ partials,  // [gridDim.x]
    int n4)                           // B/4
{
    int t = blockIdx.x * blockDim.x + threadIdx.x;
    float contrib = 0.0f;
    if (t < n4) {
        float4 xb = pb4[t];
        float4 yb = tb4[t];
        int4   lb = ts4[t];
        float xbv[4] = { xb.x, xb.y, xb.z, xb.w };
        float ybv[4] = { yb.x, yb.y, yb.z, yb.w };
        int   lbv[4] = { lb.x, lb.y, lb.z, lb.w };

        #pragma unroll
        for (int k = 0; k < 4; ++k) {
            float4 xt = pt4[(size_t)t * 4 + k];
            float4 yt = tt4[(size_t)t * 4 + k];
            size_t base = (size_t)t * 16 + (size_t)k * 4;
            float4 r0 = ps4[base + 0];
            float4 r1 = ps4[base + 1];
            float4 r2 = ps4[base + 2];
            float4 r3 = ps4[base + 3];
            float v[16] = { r0.x, r0.y, r0.z, r0.w,
                            r1.x, r1.y, r1.z, r1.w,
                            r2.x, r2.y, r2.z, r2.w,
                            r3.x, r3.y, r3.z, r3.w };
            contrib += row_contrib(xbv[k], ybv[k], xt, yt, v, lbv[k]);
        }
    }

    // wave-64 reduce
    #pragma unroll
    for (int off = 32; off > 0; off >>= 1)
        contrib += __shfl_down(contrib, off, 64);

    __shared__ float wsum[4];
    int lane = threadIdx.x & 63;
    int wave = threadIdx.x >> 6;
    if (lane == 0) wsum[wave] = contrib;
    __syncthreads();
    if (threadIdx.x == 0)
        partials[blockIdx.x] = wsum[0] + wsum[1] + wsum[2] + wsum[3];
}

__global__ __launch_bounds__(256) void reduce_kernel(
    const float* __restrict__ partials, int n,
    float* __restrict__ out, double invB)
{
    double s = 0.0;
    for (int i = threadIdx.x; i < n; i += 256)
        s += (double)partials[i];

    #pragma unroll
    for (int off = 32; off > 0; off >>= 1)
        s += __shfl_down(s, off, 64);

    __shared__ double wsum[4];
    int lane = threadIdx.x & 63;
    int wave = threadIdx.x >> 6;
    if (lane == 0) wsum[wave] = s;
    __syncthreads();
    if (threadIdx.x == 0)
        out[0] = (float)((wsum[0] + wsum[1] + wsum[2] + wsum[3]) * invB);
}

extern "C" void kernel_launch(void* const* d_in, const int* in_sizes, int n_in,
                              void* d_out, int out_size, void* d_ws, size_t ws_size,
                              hipStream_t stream) {
    const float4* pb4 = (const float4*)d_in[0];
    const float4* pt4 = (const float4*)d_in[1];
    const float4* ps4 = (const float4*)d_in[2];
    const float4* tb4 = (const float4*)d_in[3];
    const float4* tt4 = (const float4*)d_in[4];
    const int4*   ts4 = (const int4*)d_in[5];
    int B = in_sizes[0];            // 2097152, divisible by 4
    int n4 = B / 4;

    float* partials = (float*)d_ws;  // [blocks] — fully overwritten, no memset needed

    int blocks = (n4 + 255) / 256;   // 2048
    multitask_loss_kernel<<<blocks, 256, 0, stream>>>(pb4, pt4, ps4, tb4, tt4, ts4,
                                                      partials, n4);
    reduce_kernel<<<1, 256, 0, stream>>>(partials, blocks, (float*)d_out,
                                         1.0 / (double)B);
}

// Round 3
// 263.221 us; speedup vs baseline: 1.1208x; 1.0317x over previous
//
#include <hip/hip_runtime.h>
#include <math.h>
#include <stdint.h>

// Block processes LDS_ROWS consecutive rows, 1 row per thread.
#define LDS_ROWS 256
#define LDS_DW   (LDS_ROWS * 16)   // 4096 dwords = 16 KB

// Fast softplus via HW v_exp_f32/v_log_f32 (threshold is 0.117 — plenty).
__device__ __forceinline__ float fast_softplus(float x) {
    return fmaxf(x, 0.0f) + __logf(1.0f + __expf(-fabsf(x)));
}

__global__ __launch_bounds__(256) void multitask_loss_kernel(
    const float*  __restrict__ pb,   // [B]
    const float4* __restrict__ pt4,  // [B] (float4 per row)
    const float*  __restrict__ ps,   // [B*16]
    const float*  __restrict__ tb,   // [B]
    const float4* __restrict__ tt4,  // [B]
    const int*    __restrict__ ts,   // [B]
    float*        __restrict__ partials,
    int B)
{
    __shared__ float lps[LDS_DW];

    const int tid  = threadIdx.x;
    const int lane = tid & 63;
    const int wave = tid >> 6;
    const size_t row0 = (size_t)blockIdx.x * LDS_ROWS;
    const int row = (int)row0 + tid;
    const bool full_chunk = (row0 + LDS_ROWS) <= (size_t)B;

    if (full_chunk) {
        // ---- async DMA: wave w stages rows [w*64, w*64+64) of the chunk ----
        // 4 instrs x (64 lanes x 16 B) = 4 KB per wave, linear LDS layout.
        // LDS arg is the WAVE-UNIFORM base; HW lands lane i at base + i*16 B.
        const float* gsrc = ps + (row0 + (size_t)wave * 64) * 16;
        float* ldst = &lps[wave * 1024];
        #pragma unroll
        for (int j = 0; j < 4; ++j) {
            __builtin_amdgcn_global_load_lds(
                (const __attribute__((address_space(1))) void*)(gsrc + j * 256 + lane * 4),
                (__attribute__((address_space(3))) void*)(ldst + j * 256),
                16, 0, 0);
        }
    }
    __syncthreads();   // compiler emits the vmcnt drain for the LDS-DMA here

    float contrib = 0.0f;
    if (row < B) {
        // ---- direct, perfectly-coalesced small streams ----
        float  xb = pb[row];
        float  yb = tb[row];
        int    lab = ts[row];
        float4 xt = pt4[row];
        float4 yt = tt4[row];

        contrib = fast_softplus(xb) - yb * xb;           // binary BCE
        bool bin_c = (xb >= 0.0f);

        float tsum = (fast_softplus(xt.x) - yt.x * xt.x)
                   + (fast_softplus(xt.y) - yt.y * xt.y)
                   + (fast_softplus(xt.z) - yt.z * xt.z)
                   + (fast_softplus(xt.w) - yt.w * xt.w);
        contrib += 0.25f * tsum;
        bool type_c = (xt.x >= 0.0f) || (xt.y >= 0.0f) ||
                      (xt.z >= 0.0f) || (xt.w >= 0.0f);

        // ---- 16-class CE from LDS (or direct on the tail path) ----
        float v[16];
        const int rot0 = (lane + ((lane >> 4) & 1)) & 15;  // bank-spreading rotation
        if (full_chunk) {
            const int rb = tid * 16;
            #pragma unroll
            for (int d = 0; d < 16; ++d) {
                int cls = (d + rot0) & 15;               // logical class at step d
                v[d] = lps[rb + cls];                    // bank=(16*lane+cls)%32 -> 2-way only
            }
        } else {
            const float* prow = ps + (size_t)row * 16;
            #pragma unroll
            for (int d = 0; d < 16; ++d) {
                int cls = (d + rot0) & 15;
                v[d] = prow[cls];
            }
        }

        float m = -INFINITY, mr = -INFINITY, v0 = 0.0f, vlab = 0.0f;
        #pragma unroll
        for (int d = 0; d < 16; ++d) {
            int cls = (d + rot0) & 15;
            float val = v[d];
            m = fmaxf(m, val);
            if (cls == 0) v0 = val; else mr = fmaxf(mr, val);
            if (cls == lab) vlab = val;
        }
        float s = 0.0f;
        #pragma unroll
        for (int d = 0; d < 16; ++d) s += __expf(v[d] - m);
        contrib += m + __logf(s) - vlab;                 // lse - v[label]
        bool src_c = (mr > v0);                          // argmax > 0 (first-max tie-break)

        contrib += (bin_c != type_c) ? 1.0f : 0.0f;
        contrib += (bin_c != src_c)  ? 1.0f : 0.0f;
    }

    // ---- wave-64 reduce, then per-block partial ----
    #pragma unroll
    for (int off = 32; off > 0; off >>= 1)
        contrib += __shfl_down(contrib, off, 64);

    __shared__ float wsum[4];
    if (lane == 0) wsum[wave] = contrib;
    __syncthreads();
    if (tid == 0)
        partials[blockIdx.x] = wsum[0] + wsum[1] + wsum[2] + wsum[3];
}

__global__ __launch_bounds__(256) void reduce_kernel(
    const float* __restrict__ partials, int n,
    float* __restrict__ out, double invB)
{
    double s = 0.0;
    for (int i = threadIdx.x; i < n; i += 256)
        s += (double)partials[i];

    #pragma unroll
    for (int off = 32; off > 0; off >>= 1)
        s += __shfl_down(s, off, 64);

    __shared__ double wsum[4];
    int lane = threadIdx.x & 63;
    int wave = threadIdx.x >> 6;
    if (lane == 0) wsum[wave] = s;
    __syncthreads();
    if (threadIdx.x == 0)
        out[0] = (float)((wsum[0] + wsum[1] + wsum[2] + wsum[3]) * invB);
}

extern "C" void kernel_launch(void* const* d_in, const int* in_sizes, int n_in,
                              void* d_out, int out_size, void* d_ws, size_t ws_size,
                              hipStream_t stream) {
    const float*  pb  = (const float*)d_in[0];
    const float4* pt4 = (const float4*)d_in[1];
    const float*  ps  = (const float*)d_in[2];
    const float*  tb  = (const float*)d_in[3];
    const float4* tt4 = (const float4*)d_in[4];
    const int*    ts  = (const int*)d_in[5];
    int B = in_sizes[0];                      // 2097152 = 8192 * 256

    float* partials = (float*)d_ws;           // fully overwritten each call

    int blocks = (B + LDS_ROWS - 1) / LDS_ROWS;   // 8192
    multitask_loss_kernel<<<blocks, 256, 0, stream>>>(pb, pt4, ps, tb, tt4, ts,
                                                      partials, B);
    reduce_kernel<<<1, 256, 0, stream>>>(partials, blocks, (float*)d_out,
                                         1.0 / (double)B);
}